// Round 11
// baseline (20.783 us; speedup 1.0000x reference)
//
#include <hip/hip_runtime.h>

#define NN 1024
#define DD 64
#define NF 11
#define TI 16
#define G  4            // rows per sub-group
#define NG (TI / G)     // 4 sub-groups
#define BT 1024

// Softmax-without-max is exact here: valid scores are in (-1, 0], masked keys
// contribute exactly +0.0, len >= 1 so every row-sum > 0.
//
// R11: store-drain pipelining. __syncthreads() drains vmcnt(0) before
// s_barrier, serializing the 33.5MB store drain (~5.3us) after ALL compute
// (why R8's overlap was null). Here: 4 sub-groups of 4 rows, raw
// __builtin_amdgcn_s_barrier() + manual lgkmcnt(0)-only waits -> group g's
// stores stay in flight across barriers while group g+1 computes.
__global__ __launch_bounds__(BT, 8) void featuresim_kernel(
    const float* __restrict__ x,
    const int* __restrict__ x_lengths,
    const float* __restrict__ fimp,
    float* __restrict__ out)
{
    const int tid = threadIdx.x;
    const int b   = blockIdx.x >> 6;            // 64 row-groups per batch
    const int i0  = (blockIdx.x & 63) * TI;
    const int len = x_lengths[b];

    // feature_importance: uniform -> SGPRs
    float fi[NF];
    #pragma unroll
    for (int k = 0; k < NF; ++k) fi[k] = fimp[k];

    // each thread owns ONE key row j = tid (direct dwordx4, R5 style)
    float fj[NF];
    {
        const float4* p = reinterpret_cast<const float4*>(
            x + (size_t)(b * NN + tid) * DD);
        float4 a = p[0], c = p[1], d = p[2];
        fj[0] = a.x; fj[1] = a.y; fj[2]  = a.z; fj[3] = a.w;
        fj[4] = c.x; fj[5] = c.y; fj[6]  = c.z; fj[7] = c.w;
        fj[8] = d.x; fj[9] = d.y; fj[10] = d.z;
    }
    const bool valid = tid < len;

    __shared__ float partials[G][BT];     // 16 KiB (reused by all 4 groups)
    __shared__ float totals[G];

    const int lane = tid & 63;
    const int wid  = tid >> 6;

    #pragma unroll
    for (int g = 0; g < NG; ++g) {
        // ---- compute rows g*4 .. g*4+3 (VALU; q via uniform s_loads)
        float eg[G];
        #pragma unroll
        for (int rr = 0; rr < G; ++rr) {
            const int r = g * G + rr;
            const float* qp = x + (size_t)(b * NN + i0 + r) * DD;
            float s = 0.0f;
            #pragma unroll
            for (int k = 0; k < NF; ++k) {
                float d = qp[k] - fj[k];
                s = fmaf(-fabsf(d), fi[k], s);     // -abs() via VOP3 input mod
            }
            float val = (s > -1.0f) ? s : 0.0f;
            eg[rr] = valid ? __expf(val) : 0.0f;
            partials[rr][tid] = eg[rr];
        }
        asm volatile("s_waitcnt lgkmcnt(0)" ::: "memory");  // LDS writes done
        __builtin_amdgcn_s_barrier();               // (1) partials ready
        // NOTE: no vmcnt wait — previous group's stores remain in flight.

        // ---- reduce: waves 4g..4g+3 handle rows 0..3 of this group
        if ((wid >> 2) == g) {
            const int rr = wid & 3;
            float s = 0.0f;
            #pragma unroll
            for (int m = 0; m < 4; ++m) {
                float4 v4 = *reinterpret_cast<const float4*>(
                    &partials[rr][lane * 4 + 256 * m]);
                s += (v4.x + v4.y) + (v4.z + v4.w);
            }
            #pragma unroll
            for (int off = 32; off >= 1; off >>= 1)
                s += __shfl_xor(s, off, 64);
            if (lane == 0) totals[rr] = s;
        }
        asm volatile("s_waitcnt lgkmcnt(0)" ::: "memory");  // totals written
        __builtin_amdgcn_s_barrier();               // (2) totals ready

        // ---- normalize + issue stores (never waited on inside the loop)
        #pragma unroll
        for (int rr = 0; rr < G; ++rr) {
            const int r = g * G + rr;
            const float inv = __builtin_amdgcn_rcpf(totals[rr]);
            out[(size_t)(b * NN + i0 + r) * NN + tid] = eg[rr] * inv;
        }
        // partials WAR: next group's writes come after barrier (2); reduce
        // reads completed before it (explicit lgkmcnt(0)).
        // totals WAR: next group's writes come after its barrier (1); our
        // reads are forced complete by the inv use before that barrier.
    }
}

extern "C" void kernel_launch(void* const* d_in, const int* in_sizes, int n_in,
                              void* d_out, int out_size, void* d_ws, size_t ws_size,
                              hipStream_t stream) {
    const float* x    = (const float*)d_in[0];
    const int*   xlen = (const int*)d_in[1];
    const float* fimp = (const float*)d_in[2];
    float*       out  = (float*)d_out;

    const int B = in_sizes[1];                  // 8
    dim3 grid(B * (NN / TI));                   // 512 blocks = 1 resident generation
    dim3 block(BT);
    featuresim_kernel<<<grid, block, 0, stream>>>(x, xlen, fimp, out);
}

// Round 12
// 18.511 us; speedup vs baseline: 1.1228x; 1.1228x over previous
//
#include <hip/hip_runtime.h>

#define NN 1024
#define DD 64
#define NF 11
#define TI 8
#define BT 1024

// Softmax-without-max is exact here: valid scores are in (-1, 0], masked keys
// contribute exactly +0.0, len >= 1 so every row-sum > 0.
//
// R12: cross-GENERATION overlap (the one untried axis). grid = 1024 blocks of
// 1024 thr = 2x chip thread capacity -> two dispatch generations. Gen-1's
// store drain overlaps gen-2's fj-load/compute via the HW scheduler (block
// slots free at s_endpgm without waiting for store completion). All previous
// overlap attempts fought barrier semantics inside one generation and nulled.
__global__ __launch_bounds__(BT, 8) void featuresim_kernel(
    const float* __restrict__ x,
    const int* __restrict__ x_lengths,
    const float* __restrict__ fimp,
    float* __restrict__ out)
{
    const int tid = threadIdx.x;
    const int b   = blockIdx.x >> 7;            // 128 row-groups per batch
    const int i0  = (blockIdx.x & 127) * TI;
    const int len = x_lengths[b];

    // feature_importance: uniform -> SGPRs
    float fi[NF];
    #pragma unroll
    for (int k = 0; k < NF; ++k) fi[k] = fimp[k];

    // each thread owns ONE key row j = tid
    float fj[NF];
    {
        const float4* p = reinterpret_cast<const float4*>(
            x + (size_t)(b * NN + tid) * DD);
        float4 a = p[0], c = p[1], d = p[2];
        fj[0] = a.x; fj[1] = a.y; fj[2]  = a.z; fj[3] = a.w;
        fj[4] = c.x; fj[5] = c.y; fj[6]  = c.z; fj[7] = c.w;
        fj[8] = d.x; fj[9] = d.y; fj[10] = d.z;
    }
    const bool valid = tid < len;

    __shared__ float partials[TI][BT];    // 32 KiB -> 2 blocks/CU co-resident
    __shared__ float totals[TI];

    float e[TI];

    // ---- phase 1: all 8 rows (q via uniform s_loads), no barriers
    #pragma unroll
    for (int r = 0; r < TI; ++r) {
        const float* qp = x + (size_t)(b * NN + i0 + r) * DD;
        float s = 0.0f;
        #pragma unroll
        for (int k = 0; k < NF; ++k) {
            float d = qp[k] - fj[k];
            s = fmaf(-fabsf(d), fi[k], s);     // -abs() via VOP3 input mod
        }
        float val = (s > -1.0f) ? s : 0.0f;
        float ev  = valid ? __expf(val) : 0.0f;
        e[r] = ev;
        partials[r][tid] = ev;
    }
    __syncthreads();                      // (1) partials ready (no stores yet)

    // ---- phase 2: waves 0-7 reduce one row each via 4x ds_read_b128
    const int lane = tid & 63;
    const int wid  = tid >> 6;
    if (wid < TI) {
        float s = 0.0f;
        #pragma unroll
        for (int m = 0; m < 4; ++m) {
            float4 v4 = *reinterpret_cast<const float4*>(
                &partials[wid][lane * 4 + 256 * m]);
            s += (v4.x + v4.y) + (v4.z + v4.w);
        }
        #pragma unroll
        for (int off = 32; off >= 1; off >>= 1)
            s += __shfl_xor(s, off, 64);
        if (lane == 0) totals[wid] = s;
    }
    __syncthreads();                      // (2) totals ready (still no stores)

    // ---- phase 3: normalize + coalesced dword stores; kernel ends with
    // stores in flight -> drain overlaps next generation's startup.
    #pragma unroll
    for (int r = 0; r < TI; ++r) {
        const float inv = __builtin_amdgcn_rcpf(totals[r]);
        out[(size_t)(b * NN + i0 + r) * NN + tid] = e[r] * inv;
    }
}

extern "C" void kernel_launch(void* const* d_in, const int* in_sizes, int n_in,
                              void* d_out, int out_size, void* d_ws, size_t ws_size,
                              hipStream_t stream) {
    const float* x    = (const float*)d_in[0];
    const int*   xlen = (const int*)d_in[1];
    const float* fimp = (const float*)d_in[2];
    float*       out  = (float*)d_out;

    const int B = in_sizes[1];                  // 8
    dim3 grid(B * (NN / TI));                   // 1024 blocks = 2 generations
    dim3 block(BT);
    featuresim_kernel<<<grid, block, 0, stream>>>(x, xlen, fimp, out);
}

// Round 13
// 17.278 us; speedup vs baseline: 1.2028x; 1.0713x over previous
//
#include <hip/hip_runtime.h>

#define NN 1024
#define DD 64
#define NF 11
#define TI 8
#define BT 1024

// Softmax-without-max is exact here: valid scores are in (-1, 0], masked keys
// contribute exactly +0.0, len >= 1 so every row-sum > 0.
//
// R13 = R12 (2 generations, cross-gen drain overlap) + WAVE-DEAD SKIP:
// x_lengths ~ U[1,1024] -> on average ~47% of waves have base >= len and
// produce exact zeros everywhere. The check is wave-uniform (s_cbranch, no
// divergence); dead waves skip the 8x22-VALU feature loop and the rcp path,
// writing zeros to partials/out directly. Work per CU stays balanced (blocks
// from all batches mix across CUs).
__global__ __launch_bounds__(BT, 8) void featuresim_kernel(
    const float* __restrict__ x,
    const int* __restrict__ x_lengths,
    const float* __restrict__ fimp,
    float* __restrict__ out)
{
    const int tid = threadIdx.x;
    const int b   = blockIdx.x >> 7;            // 128 row-groups per batch
    const int i0  = (blockIdx.x & 127) * TI;
    const int len = x_lengths[b];

    // wave-uniform: this wave's 64 keys are all masked -> all outputs 0
    const bool wave_dead = (tid & ~63) >= len;

    __shared__ float partials[TI][BT];    // 32 KiB -> 2 blocks/CU co-resident
    __shared__ float totals[TI];

    float e[TI];

    if (wave_dead) {
        // dead waves: zeros only, no feature loop, no fj/fi loads needed
        #pragma unroll
        for (int r = 0; r < TI; ++r) {
            e[r] = 0.0f;
            partials[r][tid] = 0.0f;
        }
    } else {
        // feature_importance: uniform -> SGPRs
        float fi[NF];
        #pragma unroll
        for (int k = 0; k < NF; ++k) fi[k] = fimp[k];

        // this thread's key row j = tid
        float fj[NF];
        {
            const float4* p = reinterpret_cast<const float4*>(
                x + (size_t)(b * NN + tid) * DD);
            float4 a = p[0], c = p[1], d = p[2];
            fj[0] = a.x; fj[1] = a.y; fj[2]  = a.z; fj[3] = a.w;
            fj[4] = c.x; fj[5] = c.y; fj[6]  = c.z; fj[7] = c.w;
            fj[8] = d.x; fj[9] = d.y; fj[10] = d.z;
        }
        const bool valid = tid < len;   // partial waves still mask per-lane

        #pragma unroll
        for (int r = 0; r < TI; ++r) {
            const float* qp = x + (size_t)(b * NN + i0 + r) * DD;  // uniform -> s_load
            float s = 0.0f;
            #pragma unroll
            for (int k = 0; k < NF; ++k) {
                float d = qp[k] - fj[k];
                s = fmaf(-fabsf(d), fi[k], s);     // -abs() via VOP3 input mod
            }
            float val = (s > -1.0f) ? s : 0.0f;
            float ev  = valid ? __expf(val) : 0.0f;
            e[r] = ev;
            partials[r][tid] = ev;
        }
    }
    __syncthreads();                      // (1) partials ready (single barrier, all waves)

    // ---- phase 2: waves 0-7 reduce one row each via 4x ds_read_b128
    const int lane = tid & 63;
    const int wid  = tid >> 6;
    if (wid < TI) {
        float s = 0.0f;
        #pragma unroll
        for (int m = 0; m < 4; ++m) {
            float4 v4 = *reinterpret_cast<const float4*>(
                &partials[wid][lane * 4 + 256 * m]);
            s += (v4.x + v4.y) + (v4.z + v4.w);
        }
        #pragma unroll
        for (int off = 32; off >= 1; off >>= 1)
            s += __shfl_xor(s, off, 64);
        if (lane == 0) totals[wid] = s;
    }
    __syncthreads();                      // (2) totals ready (still no stores issued)

    // ---- phase 3: normalize + coalesced dword stores; kernel ends with
    // stores in flight -> drain overlaps next generation's startup.
    if (wave_dead) {
        #pragma unroll
        for (int r = 0; r < TI; ++r)
            out[(size_t)(b * NN + i0 + r) * NN + tid] = 0.0f;
    } else {
        #pragma unroll
        for (int r = 0; r < TI; ++r) {
            const float inv = __builtin_amdgcn_rcpf(totals[r]);
            out[(size_t)(b * NN + i0 + r) * NN + tid] = e[r] * inv;
        }
    }
}

extern "C" void kernel_launch(void* const* d_in, const int* in_sizes, int n_in,
                              void* d_out, int out_size, void* d_ws, size_t ws_size,
                              hipStream_t stream) {
    const float* x    = (const float*)d_in[0];
    const int*   xlen = (const int*)d_in[1];
    const float* fimp = (const float*)d_in[2];
    float*       out  = (float*)d_out;

    const int B = in_sizes[1];                  // 8
    dim3 grid(B * (NN / TI));                   // 1024 blocks = 2 generations
    dim3 block(BT);
    featuresim_kernel<<<grid, block, 0, stream>>>(x, xlen, fimp, out);
}